// Round 4
// baseline (111.543 us; speedup 1.0000x reference)
//
#include <hip/hip_runtime.h>
#include <stdint.h>

#define NNODE 1000
#define KSP   200
#define DIM   64
#define BATCH 8
#define WPB   4      // waves (nodes) per block

__global__ __launch_bounds__(256) void knn_edge_kernel(
    const float* __restrict__ locs,   // [B, N, 2]
    const float* __restrict__ emb,    // [B, N, 64]
    const float* __restrict__ W,      // [64]
    const float* __restrict__ bias,   // [64]
    float* __restrict__ out)
{
    __shared__ int      hist[WPB][256];   // 4 KB
    __shared__ uint64_t cand[WPB][256];   // 8 KB
    __shared__ int      cnts[WPB], ssp[WPB];

    const int tid  = threadIdx.x;
    const int w    = tid >> 6;
    const int lane = tid & 63;
    const int node = blockIdx.x * WPB + w;     // 0 .. 7999
    const int b    = node / NNODE;
    const int i    = node - b * NNODE;

    #pragma unroll
    for (int c = 0; c < 4; ++c) hist[w][c * 64 + lane] = 0;
    if (lane == 0) { cnts[w] = 0; ssp[w] = KSP + 1; }
    __builtin_amdgcn_wave_barrier();

    const float2* loc = (const float2*)(locs + (size_t)b * NNODE * 2);
    const float2 self = loc[i];

    // ---- pass 1: distances (exact XLA-matching rounding) + per-wave histogram ----
    for (int j = lane; j < NNODE; j += 64) {
        float2 p = loc[j];
        float dx = __fsub_rn(self.x, p.x);
        float dy = __fsub_rn(self.y, p.y);
        float d  = __fsqrt_rn(__fadd_rn(__fmul_rn(dx, dx), __fmul_rn(dy, dy)));
        int q = (int)(d * 180.0f);             // monotone, <= 254
        q = q > 255 ? 255 : q;
        atomicAdd(&hist[w][q], 1);
    }
    __builtin_amdgcn_wave_barrier();

    // ---- shfl-based inclusive scan over 256 bins; pick smallest bin B with cum >= 201 ----
    int base = 0, Bcand = 1 << 30;
    #pragma unroll
    for (int c = 0; c < 4; ++c) {
        int x = hist[w][c * 64 + lane];
        int sc = x;
        #pragma unroll
        for (int off = 1; off < 64; off <<= 1) {
            int y = __shfl_up(sc, off, 64);
            if (lane >= off) sc += y;
        }
        int cum = sc + base;
        if (cum >= KSP + 1 && Bcand == (1 << 30)) Bcand = c * 64 + lane;
        base += __shfl(sc, 63, 64);
    }
    #pragma unroll
    for (int off = 32; off; off >>= 1) Bcand = min(Bcand, __shfl_xor(Bcand, off, 64));
    const int B = Bcand;

    // ---- pass 2: gather candidates (recompute d; loc is L1-hot) ----
    for (int j = lane; j < NNODE; j += 64) {
        float2 p = loc[j];
        float dx = __fsub_rn(self.x, p.x);
        float dy = __fsub_rn(self.y, p.y);
        float d  = __fsqrt_rn(__fadd_rn(__fmul_rn(dx, dx), __fmul_rn(dy, dy)));
        int q = (int)(d * 180.0f);
        q = q > 255 ? 255 : q;
        if (q <= B) {
            int pos = atomicAdd(&cnts[w], 1);
            if (pos < 256) cand[w][pos] = ((uint64_t)__float_as_uint(d) << 32) | (uint32_t)j;
        }
    }
    __builtin_amdgcn_wave_barrier();
    const int cnt = min(cnts[w], 256);
    for (int t = cnt + lane; t < 256; t += 64) cand[w][t] = ~0ull;   // pad
    __builtin_amdgcn_wave_barrier();

    // ---- register bitonic sort: 256 keys, 4 per lane, e = lane*4 + r ----
    uint64_t val[4];
    #pragma unroll
    for (int r = 0; r < 4; ++r) val[r] = cand[w][(lane << 2) | r];

    for (int size = 2; size <= 256; size <<= 1) {
        for (int s = size >> 1; s > 0; s >>= 1) {
            if (s >= 4) {
                int lmask = s >> 2;
                #pragma unroll
                for (int r = 0; r < 4; ++r) {
                    uint64_t other = __shfl_xor(val[r], lmask, 64);
                    int e = (lane << 2) | r;
                    bool up  = ((e & size) == 0);
                    bool low = ((e & s) == 0);
                    uint64_t mn = val[r] < other ? val[r] : other;
                    uint64_t mx = val[r] < other ? other : val[r];
                    val[r] = (up == low) ? mn : mx;
                }
            } else {
                #pragma unroll
                for (int r = 0; r < 4; ++r) {
                    if ((r & s) == 0) {
                        int r2 = r | s;
                        int e = (lane << 2) | r;
                        bool up = ((e & size) == 0);
                        uint64_t a = val[r], c2 = val[r2];
                        bool sw = up ? (a > c2) : (a < c2);
                        if (sw) { val[r] = c2; val[r2] = a; }
                    }
                }
            }
        }
    }

    // ---- write back sorted first 201; locate self ----
    #pragma unroll
    for (int r = 0; r < 4; ++r) {
        int e = (lane << 2) | r;
        if (e <= KSP) cand[w][e] = val[r];
    }
    __builtin_amdgcn_wave_barrier();
    for (int t = lane; t <= KSP; t += 64) {
        if ((uint32_t)cand[w][t] == (uint32_t)i) atomicMin(&ssp[w], t);
    }
    __builtin_amdgcn_wave_barrier();
    const int sp = ssp[w];

    // ---- outputs: x [B*N*64] | ei0 [E] | ei1 [E] | edge_emb [E*64] ----
    const size_t E = (size_t)BATCH * NNODE * KSP;
    float* x_out = out;
    float* ei0   = out + (size_t)BATCH * NNODE * DIM;
    float* ei1   = ei0 + E;
    float* eemb  = ei1 + E;

    x_out[(size_t)node * DIM + lane] = emb[(size_t)node * DIM + lane];

    const size_t ebase = (size_t)node * KSP;
    for (int t = lane; t < KSP; t += 64) {
        int slot = t + (t >= sp ? 1 : 0);
        uint64_t kk = cand[w][slot];
        ei0[ebase + t] = (float)node;
        ei1[ebase + t] = (float)(b * NNODE + (int)(uint32_t)kk);
    }

    // per-lane W/bias registers: lane's channel group invariant across loop
    const int c4 = (lane & 15) << 2;
    const float4 w4 = *(const float4*)(W + c4);
    const float4 b4 = *(const float4*)(bias + c4);
    float4* em4 = (float4*)(eemb + ebase * DIM);
    for (int t = lane; t < KSP * (DIM / 4); t += 64) {
        int e    = t >> 4;
        int slot = e + (e >= sp ? 1 : 0);
        float d = __uint_as_float((uint32_t)(cand[w][slot] >> 32));
        float4 v;
        v.x = fmaf(d, w4.x, b4.x);
        v.y = fmaf(d, w4.y, b4.y);
        v.z = fmaf(d, w4.z, b4.z);
        v.w = fmaf(d, w4.w, b4.w);
        em4[t] = v;
    }
}

extern "C" void kernel_launch(void* const* d_in, const int* in_sizes, int n_in,
                              void* d_out, int out_size, void* d_ws, size_t ws_size,
                              hipStream_t stream) {
    const float* locs = (const float*)d_in[0];
    const float* emb  = (const float*)d_in[1];
    const float* W    = (const float*)d_in[2];
    const float* bias = (const float*)d_in[3];
    float* out = (float*)d_out;

    knn_edge_kernel<<<(BATCH * NNODE) / WPB, 256, 0, stream>>>(locs, emb, W, bias, out);
}